// Round 2
// baseline (118.154 us; speedup 1.0000x reference)
//
#include <hip/hip_runtime.h>

#define BB 8
#define TT 128
#define DD 256
#define LOG2E 1.44269504088896340736f

// Phase 1: one block per (b,t). 256 threads as 16x16; thread (ty,tx) computes
// the 16x16 sub-tile M[p][q] = exp(dec[b,p]*enc[b,t,q]), p=16ty+i, q=16tx+j,
// accumulating partial col sums (over i, per q) and row sums (over j, per p).
// Partials go to LDS via conflict-free float4 writes (pitch 260: start bank
// 4ty+16(tx&1)+4k covers all eight 4-bank groups), full sums read back
// conflict-free, and the per-(b,t) contribution enc[q]*colsum[q]/rowsum[q]
// is stored (plain coalesced store, NO atomics) to ws[(b*T+t)*D + q].
__global__ __launch_bounds__(256, 4) void attn_tile_kernel(
    const float* __restrict__ dec,   // [B, D]
    const float* __restrict__ enc,   // [B, T, D]
    float* __restrict__ ws) {        // [B, T, D] per-(b,t) contributions
    __shared__ __align__(16) float sd[DD];
    __shared__ __align__(16) float se[DD];
    __shared__ __align__(16) float scol[16 * 260];  // [ty-chunk][q], pitch 260
    __shared__ __align__(16) float srow[16 * 260];  // [tx-chunk][p], pitch 260

    const int blk = blockIdx.x;
    const int b = blk >> 7;          // / TT
    const int t = blk & (TT - 1);
    const int tid = threadIdx.x;
    const int tx = tid & 15;
    const int ty = tid >> 4;

    sd[tid] = dec[b * DD + tid];
    se[tid] = enc[(b * TT + t) * DD + tid];
    __syncthreads();

    // Stage 16 d-values (pre-scaled by log2(e)) and 16 e-values into registers.
    float dloc[16], eloc[16];
    #pragma unroll
    for (int k = 0; k < 4; ++k) {
        float4 v = *reinterpret_cast<const float4*>(&sd[ty * 16 + k * 4]);
        dloc[k * 4 + 0] = v.x * LOG2E; dloc[k * 4 + 1] = v.y * LOG2E;
        dloc[k * 4 + 2] = v.z * LOG2E; dloc[k * 4 + 3] = v.w * LOG2E;
        float4 w = *reinterpret_cast<const float4*>(&se[tx * 16 + k * 4]);
        eloc[k * 4 + 0] = w.x; eloc[k * 4 + 1] = w.y;
        eloc[k * 4 + 2] = w.z; eloc[k * 4 + 3] = w.w;
    }

    float cpart[16], rpart[16];
    #pragma unroll
    for (int j = 0; j < 16; ++j) cpart[j] = 0.0f;

    #pragma unroll
    for (int i = 0; i < 16; ++i) {
        const float di = dloc[i];
        float rs = 0.0f;
        #pragma unroll
        for (int j = 0; j < 16; ++j) {
            // exp(d*e) == exp2((d*log2e)*e): 1 mul + 1 v_exp_f32 + 2 adds
            float m = __builtin_amdgcn_exp2f(di * eloc[j]);
            rs += m;
            cpart[j] += m;
        }
        rpart[i] = rs;
    }

    // Conflict-free b128 partial writes (see bank derivation in header comment).
    #pragma unroll
    for (int k = 0; k < 4; ++k) {
        *reinterpret_cast<float4*>(&scol[ty * 260 + tx * 16 + k * 4]) =
            make_float4(cpart[k*4+0], cpart[k*4+1], cpart[k*4+2], cpart[k*4+3]);
        *reinterpret_cast<float4*>(&srow[tx * 260 + ty * 16 + k * 4]) =
            make_float4(rpart[k*4+0], rpart[k*4+1], rpart[k*4+2], rpart[k*4+3]);
    }
    __syncthreads();

    // Thread tid owns q = tid (colsum) and p = tid (rowsum); reads are
    // consecutive-lane -> conflict-free.
    float cs = 0.0f, rs = 0.0f;
    #pragma unroll
    for (int k = 0; k < 16; ++k) {
        cs += scol[k * 260 + tid];
        rs += srow[k * 260 + tid];
    }

    ws[blk * DD + tid] = se[tid] * cs / rs;
}

// Phase 2: one block per b, 1024 threads = 4 t-chunks x 256 q.
// Each thread sums 32 t-values (coalesced across lanes), LDS-reduce 4 chunks.
__global__ __launch_bounds__(1024) void reduce_t_kernel(
    const float* __restrict__ ws, float* __restrict__ out) {
    __shared__ float red[4][DD];
    const int b = blockIdx.x;
    const int q = threadIdx.x & (DD - 1);
    const int tc = threadIdx.x >> 8;   // 0..3

    const float* p = ws + (b * TT + tc * 32) * DD + q;
    float acc = 0.0f;
    #pragma unroll
    for (int t = 0; t < 32; ++t) acc += p[t * DD];
    red[tc][q] = acc;
    __syncthreads();
    if (tc == 0)
        out[b * DD + q] = red[0][q] + red[1][q] + red[2][q] + red[3][q];
}

extern "C" void kernel_launch(void* const* d_in, const int* in_sizes, int n_in,
                              void* d_out, int out_size, void* d_ws, size_t ws_size,
                              hipStream_t stream) {
    const float* dec = (const float*)d_in[0];  // [B, D] fp32
    const float* enc = (const float*)d_in[1];  // [B, T, D] fp32
    float* out = (float*)d_out;                // [B, D] fp32
    float* ws = (float*)d_ws;                  // >= B*T*D floats

    attn_tile_kernel<<<BB * TT, 256, 0, stream>>>(dec, enc, ws);
    reduce_t_kernel<<<BB, 1024, 0, stream>>>(ws, out);
}

// Round 4
// 72.112 us; speedup vs baseline: 1.6385x; 1.6385x over previous
//
#include <hip/hip_runtime.h>

#define BB 8
#define TT 128
#define DD 256
#define LOG2E 1.44269504088896340736f

// Phase 1: one block per (b,t), thread tid owns output column q = tid.
// colsum[q] = sum_p exp(dec[p]*enc[q])  -> loop over dec (LDS broadcast), own enc
// rowsum[q] = sum_r exp(dec[q]*enc[r])  -> own dec, loop over enc (LDS broadcast)
// Both sums recompute their exps (2x trans work) so each thread needs only
// ~10 live scalars: NO register arrays -> no scratch spills (R1's 237 MB of
// HBM traffic was spill traffic at VGPR_Count=64 with 64+ floats of arrays).
// All LDS reads are same-address-per-wave broadcasts: zero bank conflicts.
// exp(d*e) computed as exp2((d*log2e)*e); d*log2e hoisted (sd holds it).
__global__ __launch_bounds__(256, 4) void attn_sym_kernel(
    const float* __restrict__ dec,   // [B, D]
    const float* __restrict__ enc,   // [B, T, D]
    float* __restrict__ ws) {        // [B*T, D] per-(b,t) contributions
    __shared__ __align__(16) float sd[DD];   // dec[b,:] * log2(e)
    __shared__ __align__(16) float se[DD];   // enc[b,t,:]
    const int blk = blockIdx.x;              // b*TT + t
    const int b = blk >> 7;
    const int tid = threadIdx.x;             // q

    const float dv = dec[b * DD + tid];
    const float ev = enc[blk * DD + tid];
    const float dl2 = dv * LOG2E;
    sd[tid] = dl2;
    se[tid] = ev;
    __syncthreads();

    // 4 partial accumulators each to keep the add chains short; 8 exps of ILP
    // per iteration (8 independent v_exp_f32 in flight).
    float cs0 = 0.f, cs1 = 0.f, cs2 = 0.f, cs3 = 0.f;
    float rs0 = 0.f, rs1 = 0.f, rs2 = 0.f, rs3 = 0.f;
    #pragma unroll 8
    for (int k = 0; k < DD; k += 4) {
        float4 d4 = *reinterpret_cast<const float4*>(&sd[k]);  // broadcast
        float4 e4 = *reinterpret_cast<const float4*>(&se[k]);  // broadcast
        cs0 += __builtin_amdgcn_exp2f(d4.x * ev);
        cs1 += __builtin_amdgcn_exp2f(d4.y * ev);
        cs2 += __builtin_amdgcn_exp2f(d4.z * ev);
        cs3 += __builtin_amdgcn_exp2f(d4.w * ev);
        rs0 += __builtin_amdgcn_exp2f(dl2 * e4.x);
        rs1 += __builtin_amdgcn_exp2f(dl2 * e4.y);
        rs2 += __builtin_amdgcn_exp2f(dl2 * e4.z);
        rs3 += __builtin_amdgcn_exp2f(dl2 * e4.w);
    }
    const float cs = (cs0 + cs1) + (cs2 + cs3);
    const float rs = (rs0 + rs1) + (rs2 + rs3);

    ws[blk * DD + tid] = ev * cs / rs;
}

// Phase 2: one block per b, 256 threads; thread q strides over all T=128
// t-slices (coalesced across lanes), 8x unrolled. No cross-thread reduce
// needed: each thread owns column q outright.
__global__ __launch_bounds__(256) void reduce_t_kernel(
    const float* __restrict__ ws, float* __restrict__ out) {
    const int b = blockIdx.x;
    const int q = threadIdx.x;

    const float* p = ws + b * TT * DD + q;
    float a0 = 0.f, a1 = 0.f, a2 = 0.f, a3 = 0.f;
    #pragma unroll
    for (int t = 0; t < TT; t += 8) {
        a0 += p[(t + 0) * DD] + p[(t + 4) * DD];
        a1 += p[(t + 1) * DD] + p[(t + 5) * DD];
        a2 += p[(t + 2) * DD] + p[(t + 6) * DD];
        a3 += p[(t + 3) * DD] + p[(t + 7) * DD];
    }
    out[b * DD + q] = (a0 + a1) + (a2 + a3);
}

extern "C" void kernel_launch(void* const* d_in, const int* in_sizes, int n_in,
                              void* d_out, int out_size, void* d_ws, size_t ws_size,
                              hipStream_t stream) {
    const float* dec = (const float*)d_in[0];  // [B, D] fp32
    const float* enc = (const float*)d_in[1];  // [B, T, D] fp32
    float* out = (float*)d_out;                // [B, D] fp32
    float* ws = (float*)d_ws;                  // >= B*T*D floats

    attn_sym_kernel<<<BB * TT, 256, 0, stream>>>(dec, enc, ws);
    reduce_t_kernel<<<BB, 256, 0, stream>>>(ws, out);
}

// Round 5
// 70.725 us; speedup vs baseline: 1.6706x; 1.0196x over previous
//
#include <hip/hip_runtime.h>

#define BB 8
#define TT 128
#define DD 256
#define LOG2E 1.44269504088896340736f

// Phase 1: one block per (b,t), thread tid owns output column q = tid.
//   colsum[q] = sum_p exp(dec[p]*enc[q])   rowsum[q] = sum_r exp(dec[q]*enc[r])
// Symmetric recompute (2x exps, ~134M total) keeps live state to ~10 scalars:
// no register arrays -> no scratch spills (R1 lesson). NEW in this round: the
// broadcast operands dec[b,k] / enc[b,t,k] are BLOCK-UNIFORM, so we read them
// through uniform pointers and let the compiler emit s_load_dwordx4 (SMEM /
// constant-cache path) instead of staging through LDS. This removes the
// per-CU LDS pipe cost (2048 ds_read_b128 x ~12cyc ~= 10us/CU, the R4
// bottleneck) entirely; remaining work is 8 v_exp_f32 + 16 VALU per 4-k iter
// -> transcendental-pipe bound, ~6.8us at quarter-rate exp.
__global__ __launch_bounds__(256, 4) void attn_sym_kernel(
    const float* __restrict__ dec,   // [B, D]
    const float* __restrict__ enc,   // [B, T, D]
    float* __restrict__ ws) {        // [B*T, D] per-(b,t) contributions
    const int blk = blockIdx.x;              // b*TT + t
    const int b = blk >> 7;
    const int tid = threadIdx.x;             // q

    const float* __restrict__ drow = dec + b * DD;    // uniform pointer
    const float* __restrict__ erow = enc + blk * DD;  // uniform pointer

    const float dv = drow[tid];            // per-lane (vector load)
    const float ev = erow[tid];            // per-lane (vector load)
    const float dl2 = dv * LOG2E;          // for rowsum: exp2(dl2 * e_r)
    const float el2 = ev * LOG2E;          // for colsum: exp2(d_p * el2)

    float cs0 = 0.f, cs1 = 0.f, cs2 = 0.f, cs3 = 0.f;
    float rs0 = 0.f, rs1 = 0.f, rs2 = 0.f, rs3 = 0.f;
    #pragma unroll 8
    for (int k = 0; k < DD; k += 4) {
        // Uniform addresses -> s_load_dwordx4 (scalar pipe, no LDS/VMEM-vector)
        float4 d4 = *reinterpret_cast<const float4*>(drow + k);
        float4 e4 = *reinterpret_cast<const float4*>(erow + k);
        cs0 += __builtin_amdgcn_exp2f(d4.x * el2);
        cs1 += __builtin_amdgcn_exp2f(d4.y * el2);
        cs2 += __builtin_amdgcn_exp2f(d4.z * el2);
        cs3 += __builtin_amdgcn_exp2f(d4.w * el2);
        rs0 += __builtin_amdgcn_exp2f(dl2 * e4.x);
        rs1 += __builtin_amdgcn_exp2f(dl2 * e4.y);
        rs2 += __builtin_amdgcn_exp2f(dl2 * e4.z);
        rs3 += __builtin_amdgcn_exp2f(dl2 * e4.w);
    }
    const float cs = (cs0 + cs1) + (cs2 + cs3);
    const float rs = (rs0 + rs1) + (rs2 + rs3);

    ws[blk * DD + tid] = ev * cs / rs;
}

// Phase 2: 32 blocks = (b, 64-wide q-slice). 256 threads = 4 t-chunks x 64 q.
// Each thread sums 32 t-values (lanes 0..63 read consecutive q -> coalesced),
// then a 4-way LDS combine. 4x the CUs of the old 8-block version.
__global__ __launch_bounds__(256) void reduce_t_kernel(
    const float* __restrict__ ws, float* __restrict__ out) {
    __shared__ float red[4][64];
    const int b = blockIdx.x >> 2;
    const int qc = blockIdx.x & 3;
    const int qlane = threadIdx.x & 63;
    const int tc = threadIdx.x >> 6;         // 0..3
    const int q = qc * 64 + qlane;

    const float* p = ws + (b * TT + tc * 32) * DD + q;
    float a0 = 0.f, a1 = 0.f, a2 = 0.f, a3 = 0.f;
    #pragma unroll
    for (int t = 0; t < 32; t += 4) {
        a0 += p[(t + 0) * DD];
        a1 += p[(t + 1) * DD];
        a2 += p[(t + 2) * DD];
        a3 += p[(t + 3) * DD];
    }
    red[tc][qlane] = (a0 + a1) + (a2 + a3);
    __syncthreads();
    if (tc == 0)
        out[b * DD + q] = red[0][qlane] + red[1][qlane] +
                          red[2][qlane] + red[3][qlane];
}

extern "C" void kernel_launch(void* const* d_in, const int* in_sizes, int n_in,
                              void* d_out, int out_size, void* d_ws, size_t ws_size,
                              hipStream_t stream) {
    const float* dec = (const float*)d_in[0];  // [B, D] fp32
    const float* enc = (const float*)d_in[1];  // [B, T, D] fp32
    float* out = (float*)d_out;                // [B, D] fp32
    float* ws = (float*)d_ws;                  // >= B*T*D floats

    attn_sym_kernel<<<BB * TT, 256, 0, stream>>>(dec, enc, ws);
    reduce_t_kernel<<<BB * 4, 256, 0, stream>>>(ws, out);
}